// Round 4
// baseline (142.071 us; speedup 1.0000x reference)
//
#include <hip/hip_runtime.h>
#include <hip/hip_bf16.h>

// ---------------- problem constants ----------------
#define CHW   1048576        // 256*64*64
// ws layout (bytes)
#define XQ_BYTES 35684352u   // 16*66*66*256*2
#define WQ_OFF   35684352u   // 9*256*256*2 = 1179648
#define GNP_OFF  36864000u   // double2[1024]
#define CMM_OFF  36880384u   // float2[4096]
#define MR_OFF   36913152u   // float2[16]
#define SC_OFF   36913280u   // float[4]
#define WP_OFF   36913296u   // double[36]
#define DL_OFF   36913584u   // float delta

typedef __attribute__((ext_vector_type(8)))  short short8;
typedef __attribute__((ext_vector_type(16))) float f32x16;

__device__ __forceinline__ unsigned short f2bf(float f) {
    __hip_bfloat16 h = __float2bfloat16(f);
    return __builtin_bit_cast(unsigned short, h);
}

__device__ __forceinline__ void gload16(const void* g, void* l) {
    __builtin_amdgcn_global_load_lds(
        (const __attribute__((address_space(1))) unsigned int*)(unsigned long long)(g),
        (__attribute__((address_space(3))) unsigned int*)(unsigned int)(unsigned long long)(l),
        16, 0, 0);
}

// ---------- K1: fused per-sample sum/sumsq + per-(n,c) min/max (grid 1024, block 256) ----------
__global__ void k_pass1(const float* __restrict__ x, double2* __restrict__ part,
                        float2* __restrict__ cmm) {
    int bid = blockIdx.x;
    int n = bid >> 6, c4 = bid & 63;
    int t = threadIdx.x, ch = t >> 6, lane = t & 63;
    int c = c4 * 4 + ch;
    const float4* p = (const float4*)(x + (size_t)n * CHW + (size_t)c * 4096);
    double s = 0.0, ss = 0.0;
    float mn = 1e30f, mx = -1e30f;
#pragma unroll
    for (int k = 0; k < 16; ++k) {
        float4 v = p[k * 64 + lane];
        mn = fminf(mn, fminf(fminf(v.x, v.y), fminf(v.z, v.w)));
        mx = fmaxf(mx, fmaxf(fmaxf(v.x, v.y), fmaxf(v.z, v.w)));
        double dx = v.x, dy = v.y, dz = v.z, dw = v.w;
        s  += dx + dy + dz + dw;
        ss += dx * dx + dy * dy + dz * dz + dw * dw;
    }
    for (int o = 32; o; o >>= 1) {
        s += __shfl_down(s, o); ss += __shfl_down(ss, o);
        mn = fminf(mn, __shfl_down(mn, o)); mx = fmaxf(mx, __shfl_down(mx, o));
    }
    __shared__ double sh0[4], sh1[4];
    if (lane == 0) {
        cmm[n * 256 + c] = make_float2(mn, mx);
        sh0[ch] = s; sh1[ch] = ss;
    }
    __syncthreads();
    if (t == 0)
        part[bid] = make_double2(sh0[0] + sh0[1] + sh0[2] + sh0[3],
                                 sh1[0] + sh1[1] + sh1[2] + sh1[3]);
}

// ---------- K2: partial sum |W| (grid 36, block 256) ----------
__global__ void k_wsum(const float* __restrict__ w, double* __restrict__ wp) {
    int blk = blockIdx.x, t = threadIdx.x;
    const float4* p = (const float4*)(w + (size_t)blk * 16384);
    double s = 0.0;
#pragma unroll
    for (int j = 0; j < 16; ++j) {
        float4 v = p[j * 256 + t];
        s += fabs((double)v.x) + fabs((double)v.y) + fabs((double)v.z) + fabs((double)v.w);
    }
    for (int o = 32; o; o >>= 1) s += __shfl_down(s, o);
    __shared__ double sh[4];
    if ((t & 63) == 0) sh[t >> 6] = s;
    __syncthreads();
    if (t == 0) wp[blk] = sh[0] + sh[1] + sh[2] + sh[3];
}

// ---------- K3: all scalar reductions in one block ----------
__global__ void k_scalars(const double2* __restrict__ part, const float2* __restrict__ cmm,
                          const float* __restrict__ lnw, const float* __restrict__ lnb,
                          const double* __restrict__ wp,
                          float2* __restrict__ mr, float* __restrict__ sc,
                          float* __restrict__ dl) {
    __shared__ float shm[16], shr[16];
    int t = threadIdx.x;                 // 256
    {   // mean / rstd: t = n*16 + i
        int n = t >> 4, i = t & 15;
        double s = 0.0, ss = 0.0;
#pragma unroll
        for (int k = 0; k < 4; ++k) {
            double2 v = part[n * 64 + i * 4 + k];
            s += v.x; ss += v.y;
        }
        for (int o = 8; o; o >>= 1) { s += __shfl_down(s, o); ss += __shfl_down(ss, o); }
        if (i == 0) {
            double mean = s * (1.0 / 1048576.0);
            double var  = ss * (1.0 / 1048576.0) - mean * mean;
            shm[n] = (float)mean; shr[n] = (float)(1.0 / sqrt(var + 1e-5));
        }
    }
    __syncthreads();
    if (t < 16) mr[t] = make_float2(shm[t], shr[t]);
    // gamma from per-channel min/max (affine endpoints)
    float m = 0.0f;
#pragma unroll
    for (int k = 0; k < 16; ++k) {
        int idx = t + k * 256;
        int n = idx >> 8, c = idx & 255;
        float2 v = cmm[idx];
        float scale = lnw[c] * shr[n];
        float shift = lnb[c] - shm[n] * scale;
        m = fmaxf(m, fmaxf(fabsf(v.x * scale + shift), fabsf(v.y * scale + shift)));
    }
    for (int o = 32; o; o >>= 1) m = fmaxf(m, __shfl_down(m, o));
    __shared__ float shg[4];
    if ((t & 63) == 0) shg[t >> 6] = m;
    __syncthreads();
    if (t == 0) {
        float gamma = fmaxf(fmaxf(fmaxf(shg[0], shg[1]), fmaxf(shg[2], shg[3])), 1e-6f);
        sc[0] = gamma;
        sc[1] = 128.0f / gamma;
        sc[2] = (gamma / 128.0f) * 0.01f;
    }
    // delta
    if (t < 64) {
        double s = (t < 36) ? wp[t] : 0.0;
        for (int o = 32; o; o >>= 1) s += __shfl_down(s, o);
        if (t == 0) dl[0] = (float)(0.7 * (s / 589824.0));
    }
}

// ---------- K4: ternary quantize W -> wq[tap][co][ci] bf16 sign (grid 2304, block 256) ----------
__global__ void k_wquant(const float* __restrict__ w, const float* __restrict__ dl,
                         unsigned short* __restrict__ wq) {
    int o = blockIdx.x * 256 + threadIdx.x;   // tap*65536 + co*256 + ci
    int tap = o >> 16, rem = o & 65535, co = rem >> 8, ci = rem & 255;
    float d = dl[0];
    float v = w[co * 2304 + ci * 9 + tap];
    float s = (v > d) ? 1.0f : ((v < -d) ? -1.0f : 0.0f);
    wq[o] = f2bf(s);
}

// ---------- K5: zero only the halo of xq (grid 520, block 256) ----------
__global__ void k_halo(unsigned short* __restrict__ xq) {
    int idx = blockIdx.x * 8 + (threadIdx.x >> 5);   // 0..4159
    int n = idx / 260, p = idx - n * 260;
    int hh, ww;
    if (p < 66)       { hh = 0;        ww = p; }
    else if (p < 132) { hh = 65;       ww = p - 66; }
    else if (p < 196) { hh = p - 131;  ww = 0; }
    else              { hh = p - 195;  ww = 65; }
    uint4 z = make_uint4(0, 0, 0, 0);
    *(uint4*)(xq + ((size_t)(n * 66 + hh) * 66 + ww) * 256 + (threadIdx.x & 31) * 8) = z;
}

// ---------- K6: GN + quantize + NCHW -> padded NHWC bf16 (grid 1024, block 256) ----------
__global__ void k_quantx(const float* __restrict__ x, const float2* __restrict__ mr,
                         const float* __restrict__ sc, const float* __restrict__ lnw,
                         const float* __restrict__ lnb, unsigned short* __restrict__ xq) {
    int bid = blockIdx.x;
    int n = bid >> 6, hg = (bid >> 2) & 15, cg = bid & 3;
    int t = threadIdx.x;
    int w = t & 63, h = hg * 4 + (t >> 6);
    float2 m = mr[n];
    float s128 = sc[1];
    uint q[32];
    const float* xp = x + (((size_t)n * 256 + cg * 64) * 64 + h) * 64 + w;
#pragma unroll
    for (int ci = 0; ci < 64; ++ci) {
        int c = cg * 64 + ci;
        float g = lnw[c] * m.y;
        float be = lnb[c];
        float v = xp[(size_t)ci * 4096];
        float xs = ((v - m.x) * g + be) * s128;
        xs = fminf(fmaxf(xs, -(128.0f - 1e-6f)), (128.0f - 1e-6f));
        unsigned short ub = f2bf(rintf(xs));
        if (ci & 1) q[ci >> 1] |= ((uint)ub << 16);
        else        q[ci >> 1]  = ub;
    }
    unsigned short* op = xq + ((size_t)(n * 66 + h + 1) * 66 + (w + 1)) * 256 + cg * 64;
    uint4* o4 = (uint4*)op;
#pragma unroll
    for (int s2 = 0; s2 < 8; ++s2)
        o4[s2] = make_uint4(q[s2 * 4], q[s2 * 4 + 1], q[s2 * 4 + 2], q[s2 * 4 + 3]);
}

// ---------- K7: conv as 9-tap implicit GEMM, pipelined (tri-buffer, counted vmcnt) ----------
// grid 256 (16 n x 16 h-quads), 512 thr (8 waves 2m x 4n), tile 256(sp) x 256(co), BK=32
#define LDSB 16384   // shorts per buffer (A 8192 + B 8192)

#define MFMA8(A0,A1,A2,A3,B0,B1) \
    acc[0][0] = __builtin_amdgcn_mfma_f32_32x32x16_bf16(A0, B0, acc[0][0], 0, 0, 0); \
    acc[0][1] = __builtin_amdgcn_mfma_f32_32x32x16_bf16(A0, B1, acc[0][1], 0, 0, 0); \
    acc[1][0] = __builtin_amdgcn_mfma_f32_32x32x16_bf16(A1, B0, acc[1][0], 0, 0, 0); \
    acc[1][1] = __builtin_amdgcn_mfma_f32_32x32x16_bf16(A1, B1, acc[1][1], 0, 0, 0); \
    acc[2][0] = __builtin_amdgcn_mfma_f32_32x32x16_bf16(A2, B0, acc[2][0], 0, 0, 0); \
    acc[2][1] = __builtin_amdgcn_mfma_f32_32x32x16_bf16(A2, B1, acc[2][1], 0, 0, 0); \
    acc[3][0] = __builtin_amdgcn_mfma_f32_32x32x16_bf16(A3, B0, acc[3][0], 0, 0, 0); \
    acc[3][1] = __builtin_amdgcn_mfma_f32_32x32x16_bf16(A3, B1, acc[3][1], 0, 0, 0);

#define LD8(off) (*(const short8*)&lds[(off)])

// one chunk: 2 phases (ks=0,1); stages chunk CC+2 into SBUF; WAITM: 4 / 0 / -1
#define CHUNK(BUF, CC, SBUF, DOSTAGE, WAITM) { \
    const int _bo = (BUF) * LDSB; \
    { /* phase 0 */ \
        short8 a0 = LD8(_bo + rdA0 + p0), a1 = LD8(_bo + rdA1 + p0); \
        short8 a2 = LD8(_bo + rdA2 + p0), a3 = LD8(_bo + rdA3 + p0); \
        short8 b0 = LD8(_bo + rdB0 + p0), b1 = LD8(_bo + rdB1 + p0); \
        if (DOSTAGE) { \
            int _c2 = (CC) + 2, _tap = _c2 >> 3, _kc = _c2 & 7; \
            int _aAdd = ((_tap / 3) * 66 + (_tap % 3)) * 256 + _kc * 32; \
            gload16(xq + aOff0 + _aAdd, &lds[(SBUF) * LDSB + dA0]); \
            gload16(xq + aOff1 + _aAdd, &lds[(SBUF) * LDSB + dA1]); \
        } \
        __builtin_amdgcn_s_barrier(); \
        __builtin_amdgcn_s_setprio(1); \
        MFMA8(a0, a1, a2, a3, b0, b1) \
        __builtin_amdgcn_s_setprio(0); \
        __builtin_amdgcn_s_barrier(); \
    } \
    { /* phase 1 */ \
        short8 a0 = LD8(_bo + rdA0 + p1), a1 = LD8(_bo + rdA1 + p1); \
        short8 a2 = LD8(_bo + rdA2 + p1), a3 = LD8(_bo + rdA3 + p1); \
        short8 b0 = LD8(_bo + rdB0 + p1), b1 = LD8(_bo + rdB1 + p1); \
        if (DOSTAGE) { \
            int _c2 = (CC) + 2, _tap = _c2 >> 3, _kc = _c2 & 7; \
            int _bAdd = _tap * 65536 + _kc * 32; \
            gload16(wq + bOff0 + _bAdd, &lds[(SBUF) * LDSB + dB0]); \
            gload16(wq + bOff1 + _bAdd, &lds[(SBUF) * LDSB + dB1]); \
        } \
        __builtin_amdgcn_s_barrier(); \
        __builtin_amdgcn_s_setprio(1); \
        MFMA8(a0, a1, a2, a3, b0, b1) \
        __builtin_amdgcn_s_setprio(0); \
        if ((WAITM) == 4)      asm volatile("s_waitcnt vmcnt(4)" ::: "memory"); \
        else if ((WAITM) == 0) asm volatile("s_waitcnt vmcnt(0)" ::: "memory"); \
        __builtin_amdgcn_s_barrier(); \
    } \
}

__global__ __launch_bounds__(512, 2) void k_conv(const unsigned short* __restrict__ xq,
                                                 const unsigned short* __restrict__ wq,
                                                 const float* __restrict__ sc,
                                                 const float* __restrict__ bias,
                                                 float* __restrict__ out) {
    __shared__ unsigned short lds[3 * LDSB];   // 96 KB
    int bid = blockIdx.x;
    int n = bid >> 4, h0 = (bid & 15) << 2;
    int t = threadIdx.x, wv = t >> 6, l = t & 63;
    int wm = wv >> 2, wn = wv & 3;
    int l31 = l & 31, l5 = l >> 5;

    // ----- staging constants (per thread) -----
    int lr = l >> 2;                        // 0..15 : row within a 16-row wave-load
    int g  = (l & 3) ^ (lr & 3);            // source k-slot (involution with read swizzle)
    int rA0 = wv * 32 + lr, rA1 = rA0 + 16; // rows 0..255
    int aOff0 = ((n * 66 + h0 + (rA0 >> 6)) * 66 + (rA0 & 63)) * 256 + g * 8;
    int aOff1 = ((n * 66 + h0 + (rA1 >> 6)) * 66 + (rA1 & 63)) * 256 + g * 8;
    int bOff0 = rA0 * 256 + g * 8;
    int bOff1 = rA1 * 256 + g * 8;
    int dA0 = wv * 1024,        dA1 = wv * 1024 + 512;         // LDS elem offsets in buffer
    int dB0 = 8192 + wv * 1024, dB1 = 8192 + wv * 1024 + 512;

    // ----- read constants -----
    int q  = l31 & 3;
    int p0 = ((0 + l5) ^ q) * 8;            // ks=0 slot (elements)
    int p1 = ((2 + l5) ^ q) * 8;            // ks=1 slot
    int rdA0 = (wm * 128 +   0 + l31) * 32;
    int rdA1 = (wm * 128 +  32 + l31) * 32;
    int rdA2 = (wm * 128 +  64 + l31) * 32;
    int rdA3 = (wm * 128 +  96 + l31) * 32;
    int rdB0 = 8192 + (wn * 64 +  0 + l31) * 32;
    int rdB1 = 8192 + (wn * 64 + 32 + l31) * 32;

    f32x16 acc[4][2] = {};

    // ----- prologue: stage chunks 0 (buf0) and 1 (buf1) -----
    {
        gload16(xq + aOff0, &lds[dA0]);
        gload16(xq + aOff1, &lds[dA1]);
        gload16(wq + bOff0, &lds[dB0]);
        gload16(wq + bOff1, &lds[dB1]);
        int _aAdd = 32, _bAdd = 32;   // chunk 1: tap 0, kc 1
        gload16(xq + aOff0 + _aAdd, &lds[LDSB + dA0]);
        gload16(xq + aOff1 + _aAdd, &lds[LDSB + dA1]);
        gload16(wq + bOff0 + _bAdd, &lds[LDSB + dB0]);
        gload16(wq + bOff1 + _bAdd, &lds[LDSB + dB1]);
    }
    asm volatile("s_waitcnt vmcnt(4)" ::: "memory");
    __builtin_amdgcn_s_barrier();

    // ----- main loop: chunks 0..68 (23 x 3), staging c+2 -----
    int c = 0;
#pragma unroll 1
    for (int it = 0; it < 23; ++it) {
        CHUNK(0, c,     2, true, 4)
        CHUNK(1, c + 1, 0, true, 4)
        CHUNK(2, c + 2, 1, true, 4)
        c += 3;
    }
    CHUNK(0, 69, 2, true, 4)       // stages chunk 71 -> buf 2
    CHUNK(1, 70, 0, false, 0)      // drain: chunk 71 must be resident
    CHUNK(2, 71, 0, false, -1)

    // ----- epilogue -----
    float qs = sc[2];
    int hb = h0 + wm * 2;
#pragma unroll
    for (int mf = 0; mf < 4; ++mf) {
        int h = hb + (mf >> 1);
        int wb = (mf & 1) * 32 + l5 * 4;
#pragma unroll
        for (int nf = 0; nf < 2; ++nf) {
            int co = wn * 64 + nf * 32 + l31;
            float bv = bias[co];
            float* ob = out + ((size_t)(n * 256 + co) * 4096) + h * 64 + wb;
#pragma unroll
            for (int rg = 0; rg < 4; ++rg) {
                float4 v;
                v.x = acc[mf][nf][rg * 4 + 0] * qs + bv;
                v.y = acc[mf][nf][rg * 4 + 1] * qs + bv;
                v.z = acc[mf][nf][rg * 4 + 2] * qs + bv;
                v.w = acc[mf][nf][rg * 4 + 3] * qs + bv;
                *(float4*)(ob + rg * 8) = v;
            }
        }
    }
}

extern "C" void kernel_launch(void* const* d_in, const int* in_sizes, int n_in,
                              void* d_out, int out_size, void* d_ws, size_t ws_size,
                              hipStream_t stream) {
    (void)in_sizes; (void)n_in; (void)out_size; (void)ws_size;
    const float* x    = (const float*)d_in[0];
    const float* wgt  = (const float*)d_in[1];
    const float* bias = (const float*)d_in[2];
    const float* lnw  = (const float*)d_in[3];
    const float* lnb  = (const float*)d_in[4];
    float* out = (float*)d_out;
    char* ws = (char*)d_ws;

    unsigned short* xq = (unsigned short*)ws;
    unsigned short* wq = (unsigned short*)(ws + WQ_OFF);
    double2* gnp = (double2*)(ws + GNP_OFF);
    float2*  cmm = (float2*)(ws + CMM_OFF);
    float2*  mr  = (float2*)(ws + MR_OFF);
    float*   sc  = (float*)(ws + SC_OFF);
    double*  wp  = (double*)(ws + WP_OFF);
    float*   dl  = (float*)(ws + DL_OFF);

    k_pass1  <<<1024, 256, 0, stream>>>(x, gnp, cmm);
    k_wsum   <<<36,   256, 0, stream>>>(wgt, wp);
    k_scalars<<<1,    256, 0, stream>>>(gnp, cmm, lnw, lnb, wp, mr, sc, dl);
    k_wquant <<<2304, 256, 0, stream>>>(wgt, dl, wq);
    k_halo   <<<520,  256, 0, stream>>>(xq);
    k_quantx <<<1024, 256, 0, stream>>>(x, mr, sc, lnw, lnb, xq);
    k_conv   <<<256,  512, 0, stream>>>(xq, wq, sc, bias, out);
}

// Round 5
// 127.730 us; speedup vs baseline: 1.1123x; 1.1123x over previous
//
#include <hip/hip_runtime.h>
#include <hip/hip_bf16.h>

// ---------------- problem constants ----------------
#define CHW   1048576        // 256*64*64
// ws layout (bytes)
#define XQ_BYTES 35684352u   // 16*66*66*256*2
#define WQ_OFF   35684352u   // 9*256*256*2 = 1179648
#define GNP_OFF  36864000u   // double2[1024]
#define CMM_OFF  36880384u   // float2[4096]
#define MR_OFF   36913152u   // float2[16]
#define SC_OFF   36913280u   // float[4]
#define WP_OFF   36913296u   // double[36]
#define DL_OFF   36913584u   // float delta

typedef __attribute__((ext_vector_type(8)))  short short8;
typedef __attribute__((ext_vector_type(16))) float f32x16;

__device__ __forceinline__ unsigned short f2bf(float f) {
    __hip_bfloat16 h = __float2bfloat16(f);
    return __builtin_bit_cast(unsigned short, h);
}

__device__ __forceinline__ void gload16(const void* g, void* l) {
    __builtin_amdgcn_global_load_lds(
        (const __attribute__((address_space(1))) unsigned int*)(unsigned long long)(g),
        (__attribute__((address_space(3))) unsigned int*)(unsigned int)(unsigned long long)(l),
        16, 0, 0);
}

// ---------- K1: fused per-sample sum/sumsq + per-(n,c) min/max (grid 1024, block 256) ----------
__global__ void k_pass1(const float* __restrict__ x, double2* __restrict__ part,
                        float2* __restrict__ cmm) {
    int bid = blockIdx.x;
    int n = bid >> 6, c4 = bid & 63;
    int t = threadIdx.x, ch = t >> 6, lane = t & 63;
    int c = c4 * 4 + ch;
    const float4* p = (const float4*)(x + (size_t)n * CHW + (size_t)c * 4096);
    double s = 0.0, ss = 0.0;
    float mn = 1e30f, mx = -1e30f;
#pragma unroll
    for (int k = 0; k < 16; ++k) {
        float4 v = p[k * 64 + lane];
        mn = fminf(mn, fminf(fminf(v.x, v.y), fminf(v.z, v.w)));
        mx = fmaxf(mx, fmaxf(fmaxf(v.x, v.y), fmaxf(v.z, v.w)));
        double dx = v.x, dy = v.y, dz = v.z, dw = v.w;
        s  += dx + dy + dz + dw;
        ss += dx * dx + dy * dy + dz * dz + dw * dw;
    }
    for (int o = 32; o; o >>= 1) {
        s += __shfl_down(s, o); ss += __shfl_down(ss, o);
        mn = fminf(mn, __shfl_down(mn, o)); mx = fmaxf(mx, __shfl_down(mx, o));
    }
    __shared__ double sh0[4], sh1[4];
    if (lane == 0) {
        cmm[n * 256 + c] = make_float2(mn, mx);
        sh0[ch] = s; sh1[ch] = ss;
    }
    __syncthreads();
    if (t == 0)
        part[bid] = make_double2(sh0[0] + sh0[1] + sh0[2] + sh0[3],
                                 sh1[0] + sh1[1] + sh1[2] + sh1[3]);
}

// ---------- K2: partial sum |W| (grid 36, block 256) ----------
__global__ void k_wsum(const float* __restrict__ w, double* __restrict__ wp) {
    int blk = blockIdx.x, t = threadIdx.x;
    const float4* p = (const float4*)(w + (size_t)blk * 16384);
    double s = 0.0;
#pragma unroll
    for (int j = 0; j < 16; ++j) {
        float4 v = p[j * 256 + t];
        s += fabs((double)v.x) + fabs((double)v.y) + fabs((double)v.z) + fabs((double)v.w);
    }
    for (int o = 32; o; o >>= 1) s += __shfl_down(s, o);
    __shared__ double sh[4];
    if ((t & 63) == 0) sh[t >> 6] = s;
    __syncthreads();
    if (t == 0) wp[blk] = sh[0] + sh[1] + sh[2] + sh[3];
}

// ---------- K3: all scalar reductions in one block ----------
__global__ void k_scalars(const double2* __restrict__ part, const float2* __restrict__ cmm,
                          const float* __restrict__ lnw, const float* __restrict__ lnb,
                          const double* __restrict__ wp,
                          float2* __restrict__ mr, float* __restrict__ sc,
                          float* __restrict__ dl) {
    __shared__ float shm[16], shr[16];
    int t = threadIdx.x;                 // 256
    {   // mean / rstd: t = n*16 + i
        int n = t >> 4, i = t & 15;
        double s = 0.0, ss = 0.0;
#pragma unroll
        for (int k = 0; k < 4; ++k) {
            double2 v = part[n * 64 + i * 4 + k];
            s += v.x; ss += v.y;
        }
        for (int o = 8; o; o >>= 1) { s += __shfl_down(s, o); ss += __shfl_down(ss, o); }
        if (i == 0) {
            double mean = s * (1.0 / 1048576.0);
            double var  = ss * (1.0 / 1048576.0) - mean * mean;
            shm[n] = (float)mean; shr[n] = (float)(1.0 / sqrt(var + 1e-5));
        }
    }
    __syncthreads();
    if (t < 16) mr[t] = make_float2(shm[t], shr[t]);
    // gamma from per-channel min/max (affine endpoints)
    float m = 0.0f;
#pragma unroll
    for (int k = 0; k < 16; ++k) {
        int idx = t + k * 256;
        int n = idx >> 8, c = idx & 255;
        float2 v = cmm[idx];
        float scale = lnw[c] * shr[n];
        float shift = lnb[c] - shm[n] * scale;
        m = fmaxf(m, fmaxf(fabsf(v.x * scale + shift), fabsf(v.y * scale + shift)));
    }
    for (int o = 32; o; o >>= 1) m = fmaxf(m, __shfl_down(m, o));
    __shared__ float shg[4];
    if ((t & 63) == 0) shg[t >> 6] = m;
    __syncthreads();
    if (t == 0) {
        float gamma = fmaxf(fmaxf(fmaxf(shg[0], shg[1]), fmaxf(shg[2], shg[3])), 1e-6f);
        sc[0] = gamma;
        sc[1] = 128.0f / gamma;
        sc[2] = (gamma / 128.0f) * 0.01f;
    }
    // delta
    if (t < 64) {
        double s = (t < 36) ? wp[t] : 0.0;
        for (int o = 32; o; o >>= 1) s += __shfl_down(s, o);
        if (t == 0) dl[0] = (float)(0.7 * (s / 589824.0));
    }
}

// ---------- K4: ternary quantize W -> wq[tap][co][ci] bf16 sign (grid 2304, block 256) ----------
__global__ void k_wquant(const float* __restrict__ w, const float* __restrict__ dl,
                         unsigned short* __restrict__ wq) {
    int o = blockIdx.x * 256 + threadIdx.x;   // tap*65536 + co*256 + ci
    int tap = o >> 16, rem = o & 65535, co = rem >> 8, ci = rem & 255;
    float d = dl[0];
    float v = w[co * 2304 + ci * 9 + tap];
    float s = (v > d) ? 1.0f : ((v < -d) ? -1.0f : 0.0f);
    wq[o] = f2bf(s);
}

// ---------- K5: zero only the halo of xq (grid 520, block 256) ----------
__global__ void k_halo(unsigned short* __restrict__ xq) {
    int idx = blockIdx.x * 8 + (threadIdx.x >> 5);   // 0..4159
    int n = idx / 260, p = idx - n * 260;
    int hh, ww;
    if (p < 66)       { hh = 0;        ww = p; }
    else if (p < 132) { hh = 65;       ww = p - 66; }
    else if (p < 196) { hh = p - 131;  ww = 0; }
    else              { hh = p - 195;  ww = 65; }
    uint4 z = make_uint4(0, 0, 0, 0);
    *(uint4*)(xq + ((size_t)(n * 66 + hh) * 66 + ww) * 256 + (threadIdx.x & 31) * 8) = z;
}

// ---------- K6: GN + quantize + NCHW -> padded NHWC bf16 (grid 1024, block 256) ----------
__global__ void k_quantx(const float* __restrict__ x, const float2* __restrict__ mr,
                         const float* __restrict__ sc, const float* __restrict__ lnw,
                         const float* __restrict__ lnb, unsigned short* __restrict__ xq) {
    int bid = blockIdx.x;
    int n = bid >> 6, hg = (bid >> 2) & 15, cg = bid & 3;
    int t = threadIdx.x;
    int w = t & 63, h = hg * 4 + (t >> 6);
    float2 m = mr[n];
    float s128 = sc[1];
    uint q[32];
    const float* xp = x + (((size_t)n * 256 + cg * 64) * 64 + h) * 64 + w;
#pragma unroll
    for (int ci = 0; ci < 64; ++ci) {
        int c = cg * 64 + ci;
        float g = lnw[c] * m.y;
        float be = lnb[c];
        float v = xp[(size_t)ci * 4096];
        float xs = ((v - m.x) * g + be) * s128;
        xs = fminf(fmaxf(xs, -(128.0f - 1e-6f)), (128.0f - 1e-6f));
        unsigned short ub = f2bf(rintf(xs));
        if (ci & 1) q[ci >> 1] |= ((uint)ub << 16);
        else        q[ci >> 1]  = ub;
    }
    unsigned short* op = xq + ((size_t)(n * 66 + h + 1) * 66 + (w + 1)) * 256 + cg * 64;
    uint4* o4 = (uint4*)op;
#pragma unroll
    for (int s2 = 0; s2 < 8; ++s2)
        o4[s2] = make_uint4(q[s2 * 4], q[s2 * 4 + 1], q[s2 * 4 + 2], q[s2 * 4 + 3]);
}

// ---------- K7: conv as implicit GEMM, tri-buffer + counted vmcnt, BK=64 ----------
// grid 512 (16 n x 32 h-pairs, XCD-swizzled), 512 thr (8 waves 2m x 4n)
// tile: BM=128 spatial x BN=256 co; 36 K-steps of 64 ci (9 taps x 4)
// LDS per buffer: A 128x64 (16KB, rows 128B) + B 256x64 (32KB) = 48KB; 3 buffers = 144KB
// swizzle: 16B slot s of row r stored at phys slot s^(r&7)  (involution, conflict-free b128)
#define BUFS 24576   // shorts per buffer

#define MFMA4(Am0, Am1, Bj0, Bj1) \
    acc00 = __builtin_amdgcn_mfma_f32_32x32x16_bf16(Am0, Bj0, acc00, 0, 0, 0); \
    acc01 = __builtin_amdgcn_mfma_f32_32x32x16_bf16(Am0, Bj1, acc01, 0, 0, 0); \
    acc10 = __builtin_amdgcn_mfma_f32_32x32x16_bf16(Am1, Bj0, acc10, 0, 0, 0); \
    acc11 = __builtin_amdgcn_mfma_f32_32x32x16_bf16(Am1, Bj1, acc11, 0, 0, 0);

#define LD8(off) (*(const short8*)&lds[(off)])

// one K-step: 16 ds_read_b128 + 16 MFMA + 6 gloads (step s+2) + vmcnt(6) + 1 barrier
#define ITER(B, SB, DOSTAGE, WMODE) { \
    const int bo = (B) * BUFS; \
    short8 a00 = LD8(bo + rA0 + sp0), a10 = LD8(bo + rA1 + sp0); \
    short8 b00 = LD8(bo + rB0 + sp0), b10 = LD8(bo + rB1 + sp0); \
    short8 a01 = LD8(bo + rA0 + sp1), a11 = LD8(bo + rA1 + sp1); \
    short8 b01 = LD8(bo + rB0 + sp1), b11 = LD8(bo + rB1 + sp1); \
    if (DOSTAGE) { \
        const int so = (SB) * BUFS; \
        gload16(xq + aPix + stA,          &lds[so + dstA]); \
        gload16(xq + aPix + stA + 16896,  &lds[so + dstA + 4096]); \
        gload16(wq + bPix + stB,          &lds[so + dstB]); \
    } \
    __builtin_amdgcn_s_setprio(1); \
    MFMA4(a00, a10, b00, b10) \
    MFMA4(a01, a11, b01, b11) \
    __builtin_amdgcn_s_setprio(0); \
    short8 a02 = LD8(bo + rA0 + sp2), a12 = LD8(bo + rA1 + sp2); \
    short8 b02 = LD8(bo + rB0 + sp2), b12 = LD8(bo + rB1 + sp2); \
    short8 a03 = LD8(bo + rA0 + sp3), a13 = LD8(bo + rA1 + sp3); \
    short8 b03 = LD8(bo + rB0 + sp3), b13 = LD8(bo + rB1 + sp3); \
    if (DOSTAGE) { \
        const int so = (SB) * BUFS; \
        gload16(wq + bPix + stB + 16384, &lds[so + dstB + 4096]); \
        gload16(wq + bPix + stB + 32768, &lds[so + dstB + 8192]); \
        gload16(wq + bPix + stB + 49152, &lds[so + dstB + 12288]); \
        if (sKc < 3) { sKc++; stA += 64; stB += 64; } \
        else { sKc = 0; stB += 65344; \
               if (sTx < 2) { sTx++; stA += 64; } else { sTx = 0; stA += 16192; } } \
    } \
    __builtin_amdgcn_s_setprio(1); \
    MFMA4(a02, a12, b02, b12) \
    MFMA4(a03, a13, b03, b13) \
    __builtin_amdgcn_s_setprio(0); \
    if ((WMODE) == 6)      asm volatile("s_waitcnt vmcnt(6)" ::: "memory"); \
    else if ((WMODE) == 0) asm volatile("s_waitcnt vmcnt(0)" ::: "memory"); \
    __builtin_amdgcn_s_barrier(); \
    __builtin_amdgcn_sched_barrier(0); \
}

#define STORE4(P, A, BV) { \
    float4 v0; v0.x = (A)[0]*qs+(BV);  v0.y = (A)[1]*qs+(BV);  v0.z = (A)[2]*qs+(BV);  v0.w = (A)[3]*qs+(BV);  *(float4*)((P))      = v0; \
    float4 v1; v1.x = (A)[4]*qs+(BV);  v1.y = (A)[5]*qs+(BV);  v1.z = (A)[6]*qs+(BV);  v1.w = (A)[7]*qs+(BV);  *(float4*)((P) + 8)  = v1; \
    float4 v2; v2.x = (A)[8]*qs+(BV);  v2.y = (A)[9]*qs+(BV);  v2.z = (A)[10]*qs+(BV); v2.w = (A)[11]*qs+(BV); *(float4*)((P) + 16) = v2; \
    float4 v3; v3.x = (A)[12]*qs+(BV); v3.y = (A)[13]*qs+(BV); v3.z = (A)[14]*qs+(BV); v3.w = (A)[15]*qs+(BV); *(float4*)((P) + 24) = v3; }

__global__ __launch_bounds__(512, 2) void k_conv(const unsigned short* __restrict__ xq,
                                                 const unsigned short* __restrict__ wq,
                                                 const float* __restrict__ sc,
                                                 const float* __restrict__ bias,
                                                 float* __restrict__ out) {
    __shared__ unsigned short lds[3 * BUFS];   // 144 KB
    int t = threadIdx.x, wv = t >> 6, l = t & 63;
    int wm = wv >> 2, wn = wv & 3;
    int l31 = l & 31, l5 = l >> 5;
    int lane7 = l & 7, lane3 = l >> 3;

    // XCD-bijective swizzle (512 % 8 == 0): each XCD owns 2 consecutive samples
    int bid = ((int)blockIdx.x & 7) * 64 + ((int)blockIdx.x >> 3);
    int n = bid >> 5, h2 = (bid & 31) << 1;

    // ----- staging constants -----
    int sl8  = (lane7 ^ lane3) * 8;                       // pre-swizzled source slot
    int aPix = ((n * 66 + h2) * 66 + wv * 8 + lane3) * 256 + sl8;
    int bPix = (wv * 8 + lane3) * 256 + sl8;
    int dstA = wv * 512;                                  // wave-uniform LDS dests (shorts)
    int dstB = 8192 + wv * 512;

    // ----- read constants -----
    int rA0 = (wm * 64 +  0 + l31) * 64;
    int rA1 = (wm * 64 + 32 + l31) * 64;
    int rB0 = 8192 + (wn * 64 +  0 + l31) * 64;
    int rB1 = 8192 + (wn * 64 + 32 + l31) * 64;
    int q7  = l31 & 7;
    int sp0 = ((0 + l5) ^ q7) * 8;
    int sp1 = ((2 + l5) ^ q7) * 8;
    int sp2 = ((4 + l5) ^ q7) * 8;
    int sp3 = ((6 + l5) ^ q7) * 8;

    f32x16 acc00 = {}, acc01 = {}, acc10 = {}, acc11 = {};

    // ----- prologue: stage step 0 -> buf0, step 1 -> buf1 -----
    gload16(xq + aPix,          &lds[dstA]);
    gload16(xq + aPix + 16896,  &lds[dstA + 4096]);
    gload16(wq + bPix,          &lds[dstB]);
    gload16(wq + bPix + 16384,  &lds[dstB + 4096]);
    gload16(wq + bPix + 32768,  &lds[dstB + 8192]);
    gload16(wq + bPix + 49152,  &lds[dstB + 12288]);
    gload16(xq + aPix + 64,         &lds[BUFS + dstA]);
    gload16(xq + aPix + 16960,      &lds[BUFS + dstA + 4096]);
    gload16(wq + bPix + 64,         &lds[BUFS + dstB]);
    gload16(wq + bPix + 16448,      &lds[BUFS + dstB + 4096]);
    gload16(wq + bPix + 32832,      &lds[BUFS + dstB + 8192]);
    gload16(wq + bPix + 49216,      &lds[BUFS + dstB + 12288]);
    int stA = 128, stB = 128, sKc = 2, sTx = 0;   // next staged step = 2 (tap 0, kc 2)
    asm volatile("s_waitcnt vmcnt(6)" ::: "memory");
    __builtin_amdgcn_s_barrier();
    __builtin_amdgcn_sched_barrier(0);

    // ----- main loop: K-steps 0..32 (11 x 3), staging s+2 -----
#pragma unroll 1
    for (int it = 0; it < 11; ++it) {
        ITER(0, 2, true, 6)
        ITER(1, 0, true, 6)
        ITER(2, 1, true, 6)
    }
    ITER(0, 2, true, 6)        // s=33, stages step 35 -> buf2
    ITER(1, 0, false, 0)       // s=34, drain: step 35 must be resident
    ITER(2, 0, false, -1)      // s=35

    // ----- epilogue: C row = (reg&3)+8*(reg>>2)+4*l5 (spatial w), col = l31 (co) -----
    float qs = sc[2];
    size_t nbase = (size_t)n * CHW + (size_t)(h2 + wm) * 64;
    {
        int co0 = wn * 64 + l31;
        float bv0 = bias[co0];
        float* ob0 = out + nbase + (size_t)co0 * 4096 + l5 * 4;
        STORE4(ob0,      acc00, bv0)      // m=0: w 0..31
        STORE4(ob0 + 32, acc10, bv0)      // m=1: w 32..63
        int co1 = co0 + 32;
        float bv1 = bias[co1];
        float* ob1 = out + nbase + (size_t)co1 * 4096 + l5 * 4;
        STORE4(ob1,      acc01, bv1)
        STORE4(ob1 + 32, acc11, bv1)
    }
}

extern "C" void kernel_launch(void* const* d_in, const int* in_sizes, int n_in,
                              void* d_out, int out_size, void* d_ws, size_t ws_size,
                              hipStream_t stream) {
    (void)in_sizes; (void)n_in; (void)out_size; (void)ws_size;
    const float* x    = (const float*)d_in[0];
    const float* wgt  = (const float*)d_in[1];
    const float* bias = (const float*)d_in[2];
    const float* lnw  = (const float*)d_in[3];
    const float* lnb  = (const float*)d_in[4];
    float* out = (float*)d_out;
    char* ws = (char*)d_ws;

    unsigned short* xq = (unsigned short*)ws;
    unsigned short* wq = (unsigned short*)(ws + WQ_OFF);
    double2* gnp = (double2*)(ws + GNP_OFF);
    float2*  cmm = (float2*)(ws + CMM_OFF);
    float2*  mr  = (float2*)(ws + MR_OFF);
    float*   sc  = (float*)(ws + SC_OFF);
    double*  wp  = (double*)(ws + WP_OFF);
    float*   dl  = (float*)(ws + DL_OFF);

    k_pass1  <<<1024, 256, 0, stream>>>(x, gnp, cmm);
    k_wsum   <<<36,   256, 0, stream>>>(wgt, wp);
    k_scalars<<<1,    256, 0, stream>>>(gnp, cmm, lnw, lnb, wp, mr, sc, dl);
    k_wquant <<<2304, 256, 0, stream>>>(wgt, dl, wq);
    k_halo   <<<520,  256, 0, stream>>>(xq);
    k_quantx <<<1024, 256, 0, stream>>>(x, mr, sc, lnw, lnb, xq);
    k_conv   <<<512,  512, 0, stream>>>(xq, wq, sc, bias, out);
}

// Round 6
// 121.458 us; speedup vs baseline: 1.1697x; 1.0516x over previous
//
#include <hip/hip_runtime.h>
#include <hip/hip_bf16.h>

// ---------------- problem constants ----------------
#define CHW   1048576        // 256*64*64
// ws layout (bytes)
#define XQ_BYTES 35684352u   // 16*66*66*256*2
#define WQ_OFF   35684352u   // 9*256*256*2 = 1179648
#define GNP_OFF  36864000u   // double2[1024]
#define CMM_OFF  36880384u   // float2[4096]
#define MR_OFF   36913152u   // float2[16]
#define SC_OFF   36913280u   // float[4]
#define WP_OFF   36913296u   // double[36]
#define DL_OFF   36913584u   // float delta

typedef __attribute__((ext_vector_type(8)))  short short8;
typedef __attribute__((ext_vector_type(16))) float f32x16;

__device__ __forceinline__ unsigned short f2bf(float f) {
    __hip_bfloat16 h = __float2bfloat16(f);
    return __builtin_bit_cast(unsigned short, h);
}

__device__ __forceinline__ void gload16(const void* g, void* l) {
    __builtin_amdgcn_global_load_lds(
        (const __attribute__((address_space(1))) unsigned int*)(unsigned long long)(g),
        (__attribute__((address_space(3))) unsigned int*)(unsigned int)(unsigned long long)(l),
        16, 0, 0);
}

// ---------- K1: fused per-sample sum/sumsq + per-(n,c) min/max (grid 1024, block 256) ----------
__global__ void k_pass1(const float* __restrict__ x, double2* __restrict__ part,
                        float2* __restrict__ cmm) {
    int bid = blockIdx.x;
    int n = bid >> 6, c4 = bid & 63;
    int t = threadIdx.x, ch = t >> 6, lane = t & 63;
    int c = c4 * 4 + ch;
    const float4* p = (const float4*)(x + (size_t)n * CHW + (size_t)c * 4096);
    double s = 0.0, ss = 0.0;
    float mn = 1e30f, mx = -1e30f;
#pragma unroll
    for (int k = 0; k < 16; ++k) {
        float4 v = p[k * 64 + lane];
        mn = fminf(mn, fminf(fminf(v.x, v.y), fminf(v.z, v.w)));
        mx = fmaxf(mx, fmaxf(fmaxf(v.x, v.y), fmaxf(v.z, v.w)));
        double dx = v.x, dy = v.y, dz = v.z, dw = v.w;
        s  += dx + dy + dz + dw;
        ss += dx * dx + dy * dy + dz * dz + dw * dw;
    }
    for (int o = 32; o; o >>= 1) {
        s += __shfl_down(s, o); ss += __shfl_down(ss, o);
        mn = fminf(mn, __shfl_down(mn, o)); mx = fmaxf(mx, __shfl_down(mx, o));
    }
    __shared__ double sh0[4], sh1[4];
    if (lane == 0) {
        cmm[n * 256 + c] = make_float2(mn, mx);
        sh0[ch] = s; sh1[ch] = ss;
    }
    __syncthreads();
    if (t == 0)
        part[bid] = make_double2(sh0[0] + sh0[1] + sh0[2] + sh0[3],
                                 sh1[0] + sh1[1] + sh1[2] + sh1[3]);
}

// ---------- K2: partial sum |W| (grid 36, block 256) ----------
__global__ void k_wsum(const float* __restrict__ w, double* __restrict__ wp) {
    int blk = blockIdx.x, t = threadIdx.x;
    const float4* p = (const float4*)(w + (size_t)blk * 16384);
    double s = 0.0;
#pragma unroll
    for (int j = 0; j < 16; ++j) {
        float4 v = p[j * 256 + t];
        s += fabs((double)v.x) + fabs((double)v.y) + fabs((double)v.z) + fabs((double)v.w);
    }
    for (int o = 32; o; o >>= 1) s += __shfl_down(s, o);
    __shared__ double sh[4];
    if ((t & 63) == 0) sh[t >> 6] = s;
    __syncthreads();
    if (t == 0) wp[blk] = sh[0] + sh[1] + sh[2] + sh[3];
}

// ---------- K3: all scalar reductions in one block ----------
__global__ void k_scalars(const double2* __restrict__ part, const float2* __restrict__ cmm,
                          const float* __restrict__ lnw, const float* __restrict__ lnb,
                          const double* __restrict__ wp,
                          float2* __restrict__ mr, float* __restrict__ sc,
                          float* __restrict__ dl) {
    __shared__ float shm[16], shr[16];
    int t = threadIdx.x;                 // 256
    {   // mean / rstd: t = n*16 + i
        int n = t >> 4, i = t & 15;
        double s = 0.0, ss = 0.0;
#pragma unroll
        for (int k = 0; k < 4; ++k) {
            double2 v = part[n * 64 + i * 4 + k];
            s += v.x; ss += v.y;
        }
        for (int o = 8; o; o >>= 1) { s += __shfl_down(s, o); ss += __shfl_down(ss, o); }
        if (i == 0) {
            double mean = s * (1.0 / 1048576.0);
            double var  = ss * (1.0 / 1048576.0) - mean * mean;
            shm[n] = (float)mean; shr[n] = (float)(1.0 / sqrt(var + 1e-5));
        }
    }
    __syncthreads();
    if (t < 16) mr[t] = make_float2(shm[t], shr[t]);
    // gamma from per-channel min/max (affine endpoints)
    float m = 0.0f;
#pragma unroll
    for (int k = 0; k < 16; ++k) {
        int idx = t + k * 256;
        int n = idx >> 8, c = idx & 255;
        float2 v = cmm[idx];
        float scale = lnw[c] * shr[n];
        float shift = lnb[c] - shm[n] * scale;
        m = fmaxf(m, fmaxf(fabsf(v.x * scale + shift), fabsf(v.y * scale + shift)));
    }
    for (int o = 32; o; o >>= 1) m = fmaxf(m, __shfl_down(m, o));
    __shared__ float shg[4];
    if ((t & 63) == 0) shg[t >> 6] = m;
    __syncthreads();
    if (t == 0) {
        float gamma = fmaxf(fmaxf(fmaxf(shg[0], shg[1]), fmaxf(shg[2], shg[3])), 1e-6f);
        sc[0] = gamma;
        sc[1] = 128.0f / gamma;
        sc[2] = (gamma / 128.0f) * 0.01f;
    }
    // delta
    if (t < 64) {
        double s = (t < 36) ? wp[t] : 0.0;
        for (int o = 32; o; o >>= 1) s += __shfl_down(s, o);
        if (t == 0) dl[0] = (float)(0.7 * (s / 589824.0));
    }
}

// ---------- K4: ternary quantize W, LDS-transposed (grid 256 = one co per block) ----------
__global__ void k_wquant(const float* __restrict__ w, const float* __restrict__ dl,
                         unsigned short* __restrict__ wq) {
    __shared__ float sw[2304];
    int co = blockIdx.x, t = threadIdx.x;
    const float* wr = w + (size_t)co * 2304;
#pragma unroll
    for (int j = 0; j < 9; ++j) sw[j * 256 + t] = wr[j * 256 + t];
    __syncthreads();
    float d = dl[0];
#pragma unroll
    for (int tap = 0; tap < 9; ++tap) {
        float v = sw[t * 9 + tap];
        float s = (v > d) ? 1.0f : ((v < -d) ? -1.0f : 0.0f);
        wq[tap * 65536 + co * 256 + t] = f2bf(s);
    }
}

// ---------- K5: zero only the halo of xq (grid 520, block 256) ----------
__global__ void k_halo(unsigned short* __restrict__ xq) {
    int idx = blockIdx.x * 8 + (threadIdx.x >> 5);   // 0..4159
    int n = idx / 260, p = idx - n * 260;
    int hh, ww;
    if (p < 66)       { hh = 0;        ww = p; }
    else if (p < 132) { hh = 65;       ww = p - 66; }
    else if (p < 196) { hh = p - 131;  ww = 0; }
    else              { hh = p - 195;  ww = 65; }
    uint4 z = make_uint4(0, 0, 0, 0);
    *(uint4*)(xq + ((size_t)(n * 66 + hh) * 66 + ww) * 256 + (threadIdx.x & 31) * 8) = z;
}

// ---------- K6: GN + quantize + NCHW -> padded NHWC bf16 (grid 1024, block 256) ----------
__global__ void k_quantx(const float* __restrict__ x, const float2* __restrict__ mr,
                         const float* __restrict__ sc, const float* __restrict__ lnw,
                         const float* __restrict__ lnb, unsigned short* __restrict__ xq) {
    int bid = blockIdx.x;
    int n = bid >> 6, hg = (bid >> 2) & 15, cg = bid & 3;
    int t = threadIdx.x;
    int w = t & 63, h = hg * 4 + (t >> 6);
    float2 m = mr[n];
    float s128 = sc[1];
    uint q[32];
    const float* xp = x + (((size_t)n * 256 + cg * 64) * 64 + h) * 64 + w;
#pragma unroll
    for (int ci = 0; ci < 64; ++ci) {
        int c = cg * 64 + ci;
        float g = lnw[c] * m.y;
        float be = lnb[c];
        float v = xp[(size_t)ci * 4096];
        float xs = ((v - m.x) * g + be) * s128;
        xs = fminf(fmaxf(xs, -(128.0f - 1e-6f)), (128.0f - 1e-6f));
        unsigned short ub = f2bf(rintf(xs));
        if (ci & 1) q[ci >> 1] |= ((uint)ub << 16);
        else        q[ci >> 1]  = ub;
    }
    unsigned short* op = xq + ((size_t)(n * 66 + h + 1) * 66 + (w + 1)) * 256 + cg * 64;
    uint4* o4 = (uint4*)op;
#pragma unroll
    for (int s2 = 0; s2 < 8; ++s2)
        o4[s2] = make_uint4(q[s2 * 4], q[s2 * 4 + 1], q[s2 * 4 + 2], q[s2 * 4 + 3]);
}

// ---------- K7: conv as implicit GEMM, m201-geometry ----------
// grid 256 (16 n x 16 h-quads, XCD-swizzled), 512 thr (8 waves 2m x 4n)
// tile: BM=256 spatial (4 h-rows) x BN=256 co; per-wave 128x64 = 4x2 frags of 32x32x16
// 36 K-steps of 64 ci. LDS: A tri-buffer 3x32KB + B dbl-buffer 2x32KB = 160KB exactly.
// A prefetch distance 2 (HBM-latency safe); B distance 1 (wq is L2-resident, 1.125MB).
// swizzle: 16B slot s of 128B row r stored at phys slot s^(r&7); gload src pre-swizzled.
#define ATRI  16384   // shorts per A buffer
#define BBASE 49152   // shorts, start of B buffers
#define BBUF  16384   // shorts per B buffer

#define LD8(off) (*(const short8*)&lds[(off)])

#define STAGE_B(BS) { \
    const int _so = BBASE + (BS) * BBUF + dAB; \
    gload16(bSrc + stB,        &lds[_so]); \
    gload16(bSrc + stB + 2048, &lds[_so + 512]); \
    gload16(bSrc + stB + 4096, &lds[_so + 1024]); \
    gload16(bSrc + stB + 6144, &lds[_so + 1536]); \
    if (bKc < 3) { bKc++; stB += 64; } else { bKc = 0; stB += 65344; } }

#define STAGE_A(AS) { \
    const int _so = (AS) * ATRI + dAB; \
    gload16(aSrc + stA,        &lds[_so]); \
    gload16(aSrc + stA + 2048, &lds[_so + 512]); \
    gload16(aSrc + stA + 4096, &lds[_so + 1024]); \
    gload16(aSrc + stA + 6144, &lds[_so + 1536]); \
    if (aKc < 3) { aKc++; stA += 64; } \
    else { aKc = 0; if (aTx < 2) { aTx++; stA += 64; } else { aTx = 0; stA += 16192; } } }

// one K-step: 24 ds_read_b128 + 32 MFMA + (4 B-gload, 4 A-gload) + vmcnt(4) + 1 barrier
#define ITER(AR, BR, AS, BS, DOA, DOB, W) { \
    const int _abo = (AR) * ATRI; \
    const int _bbo = BBASE + (BR) * BBUF; \
    if (DOB) STAGE_B(BS) \
    if (DOA) STAGE_A(AS) \
    short8 b00 = LD8(_bbo + rB0 + sp0), b01 = LD8(_bbo + rB0 + sp1); \
    short8 b02 = LD8(_bbo + rB0 + sp2), b03 = LD8(_bbo + rB0 + sp3); \
    short8 b10 = LD8(_bbo + rB1 + sp0), b11 = LD8(_bbo + rB1 + sp1); \
    short8 b12 = LD8(_bbo + rB1 + sp2), b13 = LD8(_bbo + rB1 + sp3); \
    _Pragma("unroll") \
    for (int _m = 0; _m < 4; ++_m) { \
        const int _ra = _abo + rA0 + _m * 2048; \
        short8 a0 = LD8(_ra + sp0), a1 = LD8(_ra + sp1); \
        short8 a2 = LD8(_ra + sp2), a3 = LD8(_ra + sp3); \
        __builtin_amdgcn_s_setprio(1); \
        acc[_m][0] = __builtin_amdgcn_mfma_f32_32x32x16_bf16(a0, b00, acc[_m][0], 0, 0, 0); \
        acc[_m][1] = __builtin_amdgcn_mfma_f32_32x32x16_bf16(a0, b10, acc[_m][1], 0, 0, 0); \
        acc[_m][0] = __builtin_amdgcn_mfma_f32_32x32x16_bf16(a1, b01, acc[_m][0], 0, 0, 0); \
        acc[_m][1] = __builtin_amdgcn_mfma_f32_32x32x16_bf16(a1, b11, acc[_m][1], 0, 0, 0); \
        acc[_m][0] = __builtin_amdgcn_mfma_f32_32x32x16_bf16(a2, b02, acc[_m][0], 0, 0, 0); \
        acc[_m][1] = __builtin_amdgcn_mfma_f32_32x32x16_bf16(a2, b12, acc[_m][1], 0, 0, 0); \
        acc[_m][0] = __builtin_amdgcn_mfma_f32_32x32x16_bf16(a3, b03, acc[_m][0], 0, 0, 0); \
        acc[_m][1] = __builtin_amdgcn_mfma_f32_32x32x16_bf16(a3, b13, acc[_m][1], 0, 0, 0); \
        __builtin_amdgcn_s_setprio(0); \
    } \
    if ((W) == 4)      { asm volatile("s_waitcnt vmcnt(4)" ::: "memory"); } \
    else if ((W) == 0) { asm volatile("s_waitcnt vmcnt(0)" ::: "memory"); } \
    __builtin_amdgcn_s_barrier(); \
    __builtin_amdgcn_sched_barrier(0); \
}

#define STORE4(P, A, BV) { \
    float4 v0; v0.x = (A)[0]*qs+(BV);  v0.y = (A)[1]*qs+(BV);  v0.z = (A)[2]*qs+(BV);  v0.w = (A)[3]*qs+(BV);  *(float4*)((P))      = v0; \
    float4 v1; v1.x = (A)[4]*qs+(BV);  v1.y = (A)[5]*qs+(BV);  v1.z = (A)[6]*qs+(BV);  v1.w = (A)[7]*qs+(BV);  *(float4*)((P) + 8)  = v1; \
    float4 v2; v2.x = (A)[8]*qs+(BV);  v2.y = (A)[9]*qs+(BV);  v2.z = (A)[10]*qs+(BV); v2.w = (A)[11]*qs+(BV); *(float4*)((P) + 16) = v2; \
    float4 v3; v3.x = (A)[12]*qs+(BV); v3.y = (A)[13]*qs+(BV); v3.z = (A)[14]*qs+(BV); v3.w = (A)[15]*qs+(BV); *(float4*)((P) + 24) = v3; }

__global__ __launch_bounds__(512, 2) void k_conv(const unsigned short* __restrict__ xq,
                                                 const unsigned short* __restrict__ wq,
                                                 const float* __restrict__ sc,
                                                 const float* __restrict__ bias,
                                                 float* __restrict__ out) {
    __shared__ unsigned short lds[81920];   // 160 KB
    int t = threadIdx.x, wv = t >> 6, l = t & 63;
    int wm = wv >> 2, wn = wv & 3;
    int l31 = l & 31, l5 = l >> 5;

    // XCD-bijective swizzle (256 % 8 == 0): each XCD owns 32 consecutive blocks (2 samples)
    int bid = ((int)blockIdx.x & 7) * 32 + ((int)blockIdx.x >> 3);
    int n = bid >> 4, h2 = (bid & 15) << 2;

    // ----- staging constants -----
    int rowg = l >> 3;                       // row within an 8-row gload group
    int lg   = (l & 7) ^ rowg;               // pre-swizzled source slot
    const unsigned short* aSrc = xq +
        ((size_t)((n * 66 + h2 + (wv >> 1)) * 66 + (wv & 1) * 32 + rowg)) * 256 + lg * 8;
    const unsigned short* bSrc = wq + (size_t)(wv * 32 + rowg) * 256 + lg * 8;
    const int dAB = wv * 2048;               // wave-uniform LDS dest (shorts)

    // ----- read constants -----
    int q7  = l31 & 7;
    int sp0 = ((0 + l5) ^ q7) * 8;
    int sp1 = ((2 + l5) ^ q7) * 8;
    int sp2 = ((4 + l5) ^ q7) * 8;
    int sp3 = ((6 + l5) ^ q7) * 8;
    int rA0 = (wm * 128 + l31) * 64;         // + m*2048
    int rB0 = (wn * 64 + l31) * 64;
    int rB1 = rB0 + 2048;

    f32x16 acc[4][2] = {};

    // ----- prologue: A0->tri0, B0->dbuf0, A1->tri1 -----
    gload16(aSrc,        &lds[dAB]);
    gload16(aSrc + 2048, &lds[dAB + 512]);
    gload16(aSrc + 4096, &lds[dAB + 1024]);
    gload16(aSrc + 6144, &lds[dAB + 1536]);
    gload16(bSrc,        &lds[BBASE + dAB]);
    gload16(bSrc + 2048, &lds[BBASE + dAB + 512]);
    gload16(bSrc + 4096, &lds[BBASE + dAB + 1024]);
    gload16(bSrc + 6144, &lds[BBASE + dAB + 1536]);
    gload16(aSrc + 64,        &lds[ATRI + dAB]);
    gload16(aSrc + 64 + 2048, &lds[ATRI + dAB + 512]);
    gload16(aSrc + 64 + 4096, &lds[ATRI + dAB + 1024]);
    gload16(aSrc + 64 + 6144, &lds[ATRI + dAB + 1536]);
    asm volatile("s_waitcnt vmcnt(4)" ::: "memory");   // A0,B0 done; A1 in flight
    __builtin_amdgcn_s_barrier();
    __builtin_amdgcn_sched_barrier(0);

    int stA = 128, aKc = 2, aTx = 0;   // next A stage = step 2 (tap0,kc2)
    int stB = 64,  bKc = 1;            // next B stage = step 1 (tap0,kc1)

    // ----- main loop: K-steps 0..29 (5 x 6); A stages s+2, B stages s+1 -----
#pragma unroll 1
    for (int it = 0; it < 5; ++it) {
        ITER(0, 0, 2, 1, 1, 1, 4)
        ITER(1, 1, 0, 0, 1, 1, 4)
        ITER(2, 0, 1, 1, 1, 1, 4)
        ITER(0, 1, 2, 0, 1, 1, 4)
        ITER(1, 0, 0, 1, 1, 1, 4)
        ITER(2, 1, 1, 0, 1, 1, 4)
    }
    // ----- tail: K-steps 30..35 -----
    ITER(0, 0, 2, 1, 1, 1, 4)      // 30: stages A32,B31
    ITER(1, 1, 0, 0, 1, 1, 4)      // 31: stages A33,B32
    ITER(2, 0, 1, 1, 1, 1, 4)      // 32: stages A34,B33
    ITER(0, 1, 2, 0, 1, 1, 4)      // 33: stages A35,B34
    ITER(1, 0, 0, 1, 0, 1, 0)      // 34: stages B35; drain
    ITER(2, 1, 0, 0, 0, 0, -1)     // 35

    // ----- epilogue: C row = (reg&3)+8*(reg>>2)+4*l5 (spatial w), col = l31 (co) -----
    float qs = sc[2];
#pragma unroll
    for (int m = 0; m < 4; ++m) {
        int h = h2 + wm * 2 + (m >> 1);
        int wb = (m & 1) * 32 + l5 * 4;
        size_t obase = (size_t)n * CHW + (size_t)h * 64 + wb;
#pragma unroll
        for (int nf = 0; nf < 2; ++nf) {
            int co = wn * 64 + nf * 32 + l31;
            float bv = bias[co];
            float* ob = out + obase + (size_t)co * 4096;
            STORE4(ob, acc[m][nf], bv)
        }
    }
}

extern "C" void kernel_launch(void* const* d_in, const int* in_sizes, int n_in,
                              void* d_out, int out_size, void* d_ws, size_t ws_size,
                              hipStream_t stream) {
    (void)in_sizes; (void)n_in; (void)out_size; (void)ws_size;
    const float* x    = (const float*)d_in[0];
    const float* wgt  = (const float*)d_in[1];
    const float* bias = (const float*)d_in[2];
    const float* lnw  = (const float*)d_in[3];
    const float* lnb  = (const float*)d_in[4];
    float* out = (float*)d_out;
    char* ws = (char*)d_ws;

    unsigned short* xq = (unsigned short*)ws;
    unsigned short* wq = (unsigned short*)(ws + WQ_OFF);
    double2* gnp = (double2*)(ws + GNP_OFF);
    float2*  cmm = (float2*)(ws + CMM_OFF);
    float2*  mr  = (float2*)(ws + MR_OFF);
    float*   sc  = (float*)(ws + SC_OFF);
    double*  wp  = (double*)(ws + WP_OFF);
    float*   dl  = (float*)(ws + DL_OFF);

    k_pass1  <<<1024, 256, 0, stream>>>(x, gnp, cmm);
    k_wsum   <<<36,   256, 0, stream>>>(wgt, wp);
    k_scalars<<<1,    256, 0, stream>>>(gnp, cmm, lnw, lnb, wp, mr, sc, dl);
    k_wquant <<<256,  256, 0, stream>>>(wgt, dl, wq);
    k_halo   <<<520,  256, 0, stream>>>(xq);
    k_quantx <<<1024, 256, 0, stream>>>(x, mr, sc, lnw, lnb, xq);
    k_conv   <<<256,  512, 0, stream>>>(xq, wq, sc, bias, out);
}